// Round 6
// baseline (273.825 us; speedup 1.0000x reference)
//
#include <hip/hip_runtime.h>
#include <stdint.h>

// ---------------------------------------------------------------------------
// Problem: B=2, S=2048, E=64, H=12, D=128, inner=1536
// Pipeline: [rope table] -> [QKV proj + RoPE -> bf16 (Q pre-scaled)] ->
//           [causal flash attn, split-K x4 within 1024-thr block, K+V in LDS,
//            32x32 MFMA, no-max softmax, + Wo cast in light blocks] ->
//           [output proj]
// ---------------------------------------------------------------------------

typedef short v8s __attribute__((ext_vector_type(8)));    // 8 x bf16
typedef unsigned int v4u __attribute__((ext_vector_type(4)));
typedef float v4f __attribute__((ext_vector_type(4)));
typedef float v16f __attribute__((ext_vector_type(16)));

#define MFMA16(a, b, c) __builtin_amdgcn_mfma_f32_16x16x32_bf16(a, b, c, 0, 0, 0)
#define MFMA32(a, b, c) __builtin_amdgcn_mfma_f32_32x32x16_bf16(a, b, c, 0, 0, 0)

#if __has_builtin(__builtin_amdgcn_exp2f)
#define EXP2(x) __builtin_amdgcn_exp2f(x)
#else
#define EXP2(x) exp2f(x)
#endif

// 1/sqrt(128) * log2(e): folded into Q at projection time
#define SCALE2 (0.08838834764831845f * 1.4426950408889634f)

__device__ __forceinline__ unsigned short f2bf(float f) {
  uint32_t u = __builtin_bit_cast(uint32_t, f);
  u += 0x7FFFu + ((u >> 16) & 1u);   // round-to-nearest-even
  return (unsigned short)(u >> 16);
}

// pack two fp32 -> bf16x2 word (round-half-up) via 2 adds + v_perm_b32
__device__ __forceinline__ uint32_t packbf(float lo, float hi) {
  return __builtin_amdgcn_perm(__builtin_bit_cast(uint32_t, hi) + 0x8000u,
                               __builtin_bit_cast(uint32_t, lo) + 0x8000u,
                               0x07060302u);
}

__device__ __forceinline__ v16f zero16() {
  v16f z;
#pragma unroll
  for (int i = 0; i < 16; ++i) z[i] = 0.f;
  return z;
}

// async global->LDS, 16 B per lane. LDS dst must be wave-uniform base + lane*16.
__device__ __forceinline__ void gl_lds16(const unsigned short* g, unsigned short* l) {
  __builtin_amdgcn_global_load_lds(
      (const __attribute__((address_space(1))) uint32_t*)g,
      (__attribute__((address_space(3))) uint32_t*)l, 16, 0, 0);
}

// ---------------------------------------------------------------------------
// Kernel 0: rope cos/sin table [S=2048][half=64]
// ---------------------------------------------------------------------------
__global__ __launch_bounds__(256) void rope_table(float* __restrict__ cos_t,
                                                  float* __restrict__ sin_t) {
  int idx = blockIdx.x * 256 + threadIdx.x;
  if (idx >= 2048 * 64) return;
  int s = idx >> 6, f = idx & 63;
  // 10000^(-f/64) = exp2(-f * log2(10000)/64)
  float inv = exp2f((float)f * -0.20762050593046014f);
  float ang = (float)s * inv;
  float si, co;
  sincosf(ang, &si, &co);
  cos_t[idx] = co;
  sin_t[idx] = si;
}

// ---------------------------------------------------------------------------
// Kernel 1: QKV projection + RoPE + bf16 cast, LDS-staged coalesced output.
// Q additionally scaled by SCALE2 (rotation commutes with scaling).
// qh/kh: bf16 [B,H,S,D].
// V written FRAGMENT-LINEAR for attn's LDS-staged PV reads:
//   vtf[bh][kt=tok/64][G=chunk/2 (4)][dt=d/32 (4)][lane=hh*32+(d&31) (64)][8 keys]
//   where chunk=(tok%64)/8, hh=chunk&1, G=chunk>>1.
//   Each (G,dt) block = 64 lanes x 16B contiguous; a 32-key subtile (2 G's)
//   is a contiguous 8 KB run -> trivial gl_lds16 copy, conflict-free b128.
// ---------------------------------------------------------------------------
__global__ __launch_bounds__(256) void proj_rope(
    const float* __restrict__ x, const float* __restrict__ Wq,
    const float* __restrict__ Wk, const float* __restrict__ Wv,
    const float* __restrict__ cos_t, const float* __restrict__ sin_t,
    unsigned short* __restrict__ qh, unsigned short* __restrict__ kh,
    unsigned short* __restrict__ vt) {
  const int wave = threadIdx.x >> 6, lane = threadIdx.x & 63;
  const int l16 = lane & 15, quad = lane >> 4;
  const int by = blockIdx.y;
  const int o_base = by * 64 + wave * 16;
  const int mat = o_base / 1536;                    // 0=q 1=k 2=v (block-uniform)
  const int inner0 = o_base % 1536;
  const int d0w = inner0 & 127;
  const float* Wsrc = (mat == 0) ? Wq : ((mat == 1) ? Wk : Wv);
  const float qscale = (mat == 0) ? SCALE2 : 1.0f;

  __shared__ __align__(16) unsigned short Lt[64][72];

  v8s wb[2];
  {
    const float* wr = Wsrc + (size_t)(inner0 + l16) * 64 + quad * 8;
#pragma unroll
    for (int s = 0; s < 2; ++s) {
      float4 a = *(const float4*)(wr + s * 32);
      float4 b = *(const float4*)(wr + s * 32 + 4);
      v8s t;
      t[0] = (short)f2bf(a.x); t[1] = (short)f2bf(a.y);
      t[2] = (short)f2bf(a.z); t[3] = (short)f2bf(a.w);
      t[4] = (short)f2bf(b.x); t[5] = (short)f2bf(b.y);
      t[6] = (short)f2bf(b.z); t[7] = (short)f2bf(b.w);
      wb[s] = t;
    }
  }

  const int d = d0w + l16;
  const int half = d >> 1;

#pragma unroll
  for (int i = 0; i < 4; ++i) {
    const int tok0 = blockIdx.x * 64 + i * 16;
    const float* xr = x + (size_t)(tok0 + l16) * 64 + quad * 8;
    v8s xa[2];
#pragma unroll
    for (int s = 0; s < 2; ++s) {
      float4 a = *(const float4*)(xr + s * 32);
      float4 b = *(const float4*)(xr + s * 32 + 4);
      v8s t;
      t[0] = (short)f2bf(a.x); t[1] = (short)f2bf(a.y);
      t[2] = (short)f2bf(a.z); t[3] = (short)f2bf(a.w);
      t[4] = (short)f2bf(b.x); t[5] = (short)f2bf(b.y);
      t[6] = (short)f2bf(b.z); t[7] = (short)f2bf(b.w);
      xa[s] = t;
    }
    v4f acc = {0.f, 0.f, 0.f, 0.f};
    acc = MFMA16(xa[0], wb[0], acc);
    acc = MFMA16(xa[1], wb[1], acc);

    if (mat < 2) {
#pragma unroll
      for (int r = 0; r < 4; ++r) {
        int sidx = (tok0 + quad * 4 + r) & 2047;
        float val = acc[r];
        float prt = __shfl_xor(val, 1);   // pair partner (d^1), same token
        float co = cos_t[sidx * 64 + half];
        float si = sin_t[sidx * 64 + half];
        float rot = ((d & 1) == 0) ? (val * co - prt * si)
                                   : (prt * si + val * co);
        Lt[i * 16 + quad * 4 + r][wave * 16 + l16] = f2bf(rot * qscale);
      }
    } else {
#pragma unroll
      for (int r = 0; r < 4; ++r)
        Lt[wave * 16 + l16][i * 16 + quad * 4 + r] = f2bf(acc[r]);
    }
  }
  __syncthreads();

  // cooperative b128 coalesced readout
  const int matb = (by * 64) / 1536;
  const int innerb = (by * 64) % 1536;
  const int hb = innerb >> 7;
  const int d0b = innerb & 127;
  const int b = (blockIdx.x * 64) >> 11;
  const int tokbase = (blockIdx.x * 64) & 2047;
#pragma unroll
  for (int jj = 0; jj < 2; ++jj) {
    int cid = jj * 256 + threadIdx.x;
    int outer = cid >> 3, ic = cid & 7;
    v8s val = *(const v8s*)&Lt[outer][ic * 8];
    if (matb < 2) {
      unsigned short* dst = (matb == 0 ? qh : kh) +
          (((size_t)(b * 12 + hb)) * 2048 + tokbase + outer) * 128 + d0b + ic * 8;
      *(v8s*)dst = val;
    } else {
      // fragment-linear vtf store: Lt[outer][ic*8+e] = V^T[d0b+outer][tokbase+ic*8+e]
      const int kt = tokbase >> 6;
      const int G = ic >> 1, hhb = ic & 1;
      const int dd = d0b + outer;
      unsigned short* dst = vt +
          ((((((size_t)(b * 12 + hb)) * 32 + kt) * 4 + G) * 4 + (dd >> 5)) * 64 +
           hhb * 32 + (dd & 31)) * 8;
      *(v8s*)dst = val;
    }
  }
}

// ---------------------------------------------------------------------------
// Kernel 2: causal flash attention, SPLIT-K x4 within 1024-thread block.
// R5 post-mortem: all measured floors (MFMA 3us, LDS-read 16us, L2 6us, VALU
// 8us) sum to ~33us vs 59 measured, nothing >30% utilized -> latency-exposed
// at 2 waves/SIMD (128KB LDS -> 1 block/CU -> 8 waves). Fix: 16 waves/block
// (4 row-groups x 4 key-herds), 32-key tiles, NS=qb+1 steps. Critical block:
// half the serial per-step work AND 4 waves/SIMD for latency hiding.
// LDS: 4 herds x dbuf x (8K K + 8K V) = 128KB dynamic. Exact linear 4-way
// combine (no max-rescale): phased epilogue overlaying the K/V area
//   (A) herds 2,3 dump O fp32 (128KB exactly)  (B) herds 0,1 accumulate
//   (C) herd 1 re-dumps O (64KB) + herds 1-3 dump lsum  (D) herd 0 finalizes.
// Queue balance (1 block/CU, 384 blocks): singles n in [128,256) get the
// heaviest blocks (qb 15..11 + 8x qb10); pairs (n, n+256) sum to 12 units
// under CU(n)=n%256 round-robin; worst CU = 16 units at half step-cost.
// qb==0 blocks (lightest) also cast Wo->bf16 into the dead cos-table region.
// ---------------------------------------------------------------------------
__global__ __launch_bounds__(1024, 4) void attn(
    const unsigned short* __restrict__ qh, const unsigned short* __restrict__ kh,
    const unsigned short* __restrict__ vtf, unsigned short* __restrict__ att,
    const float* __restrict__ Wo, unsigned short* __restrict__ wob) {
  extern __shared__ __align__(16) unsigned short SH[];
  unsigned short* KSH = SH;            // 8 slots (herd*2+buf) x 4096 shorts [64 KB]
  unsigned short* VSH = SH + 32768;    // 8 slots x 4096 shorts              [64 KB]

  // ---- balanced decode: singles = heaviest, pairs sum to 12 (see header)
  const int n = blockIdx.x;
  int qb, bh;
  if (n >= 128 && n < 256) {            // singles
    int r = n - 128;
    if (r < 120) { qb = 15 - r / 24; bh = r % 24; }   // qb 15..11
    else         { qb = 10; bh = r - 120; }           // 8 of qb10 (bh 0..7)
  } else if (n < 128) {                 // pair primaries
    if (n < 16)       { qb = 10; bh = 8 + n; }
    else if (n < 40)  { qb = 9;  bh = n - 16; }
    else if (n < 64)  { qb = 8;  bh = n - 40; }
    else if (n < 88)  { qb = 7;  bh = n - 64; }
    else if (n < 112) { qb = 6;  bh = n - 88; }
    else if (n < 124) { qb = 5;  bh = n - 112; }      // first 12 of qb5
    else              { qb = 0;  bh = n - 124; }      // bh 0..3
  } else {                              // n in [256,384): pair secondaries
    int r = n - 256;
    if (r < 16)       { qb = 0; bh = 8 + r; }         // bh 8..23
    else if (r < 40)  { qb = 1; bh = r - 16; }
    else if (r < 64)  { qb = 2; bh = r - 40; }
    else if (r < 88)  { qb = 3; bh = r - 64; }
    else if (r < 112) { qb = 4; bh = r - 88; }
    else if (r < 124) { qb = 5; bh = 12 + (r - 112); }// last 12 of qb5
    else              { qb = 0; bh = 4 + (r - 124); } // bh 4..7
  }

  const int t = threadIdx.x;
  const int lane = t & 63;
  const int l31 = lane & 31, hh = lane >> 5;
  const int w = t >> 6;                          // 16 waves
  const int rg = w & 3, kherd = w >> 2;          // row-group / key-quarter
  const int r0w = qb * 128 + rg * 32;
  const int qrow = r0w + l31;
  const int rowmax = r0w + 31;

  const unsigned short* Qb = qh + (size_t)bh * 2048 * 128;
  const unsigned short* Kb = kh + (size_t)bh * 2048 * 128;
  const unsigned short* Vb = vtf + (size_t)bh * 262144;   // 32*4*4*64*8

  // Q fragments (serve as MFMA B-operand): Q[qrow][ks*16 + hh*8 + j]
  v8s qa[8];
  {
    const unsigned short* qr = Qb + (size_t)qrow * 128 + hh * 8;
#pragma unroll
    for (int ks = 0; ks < 8; ++ks) qa[ks] = *(const v8s*)(qr + ks * 16);
  }

  const int NS = qb + 1;                 // steps; herd h owns tiles h*NS+i

  // staging: per step, 1024 threads move 4x(8K K + 8K V).
  // t<512: K of herd j (global swizzle: chunk (key,c) holds d-chunk c^(key&15))
  // t>=512: V of herd j (fragment-linear -> identity copy)
  const int th = t & 511;
  const int kr = th >> 4, kc = th & 15;
  const int offK = kr * 128 + ((kc ^ (kr & 15)) << 3);
  auto stage = [&](int i1) {             // stage step i1 for all 4 herds
#pragma unroll
    for (int j = 0; j < 4; ++j) {
      const int kt = j * NS + i1;
      const int slot = j * 2 + (i1 & 1);
      if (t < 512) {
        gl_lds16(Kb + (size_t)(kt << 5) * 128 + offK, KSH + slot * 4096 + (th << 3));
      } else {
        gl_lds16(Vb + (size_t)kt * 4096 + (th << 3), VSH + slot * 4096 + (th << 3));
      }
    }
  };

  v16f O[4];
#pragma unroll
  for (int i = 0; i < 4; ++i) O[i] = zero16();
  float lsum = 0.f;

  stage(0);
  asm volatile("s_waitcnt vmcnt(0)" ::: "memory");

  for (int i = 0; i < NS; ++i) {
    __builtin_amdgcn_s_barrier();          // publishes step-i tiles (all herds)
    __builtin_amdgcn_sched_barrier(0);
    const int kt = kherd * NS + i;
    const int key0 = kt << 5;
    const bool active = key0 <= rowmax;

    // ---- next step's DMA (issued first; covered by compute)
    if (i + 1 < NS) stage(i + 1);
    __builtin_amdgcn_sched_barrier(0);

    if (active) {
      const unsigned short* Kl = KSH + (kherd * 2 + (i & 1)) * 4096;
      const unsigned short* Vl = VSH + (kherd * 2 + (i & 1)) * 4096;
      const bool mask0 = (key0 + 31) > r0w;

      // ---- S^T = K·Q^T (two independent 4-deep chains)
      v16f Sa = zero16(), Sb = zero16();
      __builtin_amdgcn_s_setprio(1);
#pragma unroll
      for (int ks = 0; ks < 8; ks += 2) {
        v8s ka0 = *(const v8s*)(
            Kl + ((l31 * 16 + ((2 * ks + hh) ^ (l31 & 15))) << 3));
        v8s ka1 = *(const v8s*)(
            Kl + ((l31 * 16 + ((2 * ks + 2 + hh) ^ (l31 & 15))) << 3));
        Sa = MFMA32(ka0, qa[ks], Sa);
        Sb = MFMA32(ka1, qa[ks + 1], Sb);
      }
      __builtin_amdgcn_s_setprio(0);

      // ---- softpack: S^T tile -> packed bf16 P-words + lsum
      uint32_t W[8];
#pragma unroll
      for (int m = 0; m < 8; ++m) {
        float pa = EXP2(Sa[2 * m] + Sb[2 * m]);
        float pb = EXP2(Sa[2 * m + 1] + Sb[2 * m + 1]);
        if (mask0) {
          int keyb = key0 + 2 * (m & 1) + 8 * (m >> 1) + 4 * hh;
          pa = (keyb <= qrow) ? pa : 0.f;
          pb = (keyb + 1 <= qrow) ? pb : 0.f;
        }
        lsum += pa + pb;
        W[m] = packbf(pa, pb);
      }

      // ---- pv: build B-operand P frags (word swap across lane^32), mult V^T
      uint32_t r0 = __shfl_xor(hh ? W[0] : W[2], 32);
      uint32_t r1 = __shfl_xor(hh ? W[1] : W[3], 32);
      uint32_t r2 = __shfl_xor(hh ? W[4] : W[6], 32);
      uint32_t r3 = __shfl_xor(hh ? W[5] : W[7], 32);
#pragma unroll
      for (int g = 0; g < 2; ++g) {
        if (key0 + g * 16 > rowmax) continue;   // wave-uniform skip
        uint32_t rA = g ? r2 : r0, rB = g ? r3 : r1;
        v4u fw;
        fw.x = hh ? rA : W[4 * g];
        fw.y = hh ? rB : W[4 * g + 1];
        fw.z = hh ? W[4 * g + 2] : rA;
        fw.w = hh ? W[4 * g + 3] : rB;
        v8s pfrag = __builtin_bit_cast(v8s, fw);
        __builtin_amdgcn_s_setprio(1);
#pragma unroll
        for (int dt = 0; dt < 4; ++dt) {
          v8s va = *(const v8s*)(Vl + (((g * 4 + dt) * 64 + lane) << 3));
          O[dt] = MFMA32(va, pfrag, O[dt]);
        }
        __builtin_amdgcn_s_setprio(0);
      }
    }
    // staged DMA must retire before next barrier publishes the buffers
    asm volatile("s_waitcnt vmcnt(0)" ::: "memory");
  }

  // ---- 4-way split-K reduce, phased over the 128KB K/V area (dead now)
  __syncthreads();
  float* R = (float*)SH;                 // 32768 floats
  if (kherd >= 2) {                      // (A) herds 2,3 dump O
    float* baseO = R + (kherd - 2) * 16384 + rg * 4096 + l31 * 128;
#pragma unroll
    for (int dt = 0; dt < 4; ++dt)
#pragma unroll
      for (int pr = 0; pr < 4; ++pr) {
        float4 v;
        v.x = O[dt][4 * pr + 0]; v.y = O[dt][4 * pr + 1];
        v.z = O[dt][4 * pr + 2]; v.w = O[dt][4 * pr + 3];
        *(float4*)(baseO + dt * 32 + (((2 * pr + hh) ^ (l31 & 7)) << 2)) = v;
      }
  }
  __syncthreads();
  if (kherd < 2) {                       // (B) herd 0 += herd 2; herd 1 += herd 3
    const float* baseO = R + kherd * 16384 + rg * 4096 + l31 * 128;
#pragma unroll
    for (int dt = 0; dt < 4; ++dt)
#pragma unroll
      for (int pr = 0; pr < 4; ++pr) {
        float4 v = *(const float4*)(
            baseO + dt * 32 + (((2 * pr + hh) ^ (l31 & 7)) << 2));
        O[dt][4 * pr + 0] += v.x;
        O[dt][4 * pr + 1] += v.y;
        O[dt][4 * pr + 2] += v.z;
        O[dt][4 * pr + 3] += v.w;
      }
  }
  __syncthreads();
  if (kherd == 1) {                      // (C) herd 1 dumps combined O
    float* baseO = R + rg * 4096 + l31 * 128;
#pragma unroll
    for (int dt = 0; dt < 4; ++dt)
#pragma unroll
      for (int pr = 0; pr < 4; ++pr) {
        float4 v;
        v.x = O[dt][4 * pr + 0]; v.y = O[dt][4 * pr + 1];
        v.z = O[dt][4 * pr + 2]; v.w = O[dt][4 * pr + 3];
        *(float4*)(baseO + dt * 32 + (((2 * pr + hh) ^ (l31 & 7)) << 2)) = v;
      }
  }
  if (kherd >= 1)                        // (C) herds 1..3 dump lsum
    R[16384 + (kherd - 1) * 256 + rg * 64 + lane] = lsum;
  __syncthreads();
  if (kherd == 0) {                      // (D) finalize + store
    const float* baseO = R + rg * 4096 + l31 * 128;
    float lt = lsum + R[16384 + rg * 64 + lane] +
               R[16384 + 256 + rg * 64 + lane] + R[16384 + 512 + rg * 64 + lane];
    const float tot = lt + __shfl_xor(lt, 32);
    const float inv = 1.0f / tot;
    const int b = bh / 12, hq = bh % 12;
    unsigned short* arow = att + ((size_t)b * 2048 + qrow) * 1536 + hq * 128;
#pragma unroll
    for (int dt = 0; dt < 4; ++dt) {
#pragma unroll
      for (int pr = 0; pr < 4; ++pr) {
        float4 v = *(const float4*)(
            baseO + dt * 32 + (((2 * pr + hh) ^ (l31 & 7)) << 2));
        float a0 = (O[dt][4 * pr + 0] + v.x) * inv;
        float a1 = (O[dt][4 * pr + 1] + v.y) * inv;
        float a2 = (O[dt][4 * pr + 2] + v.z) * inv;
        float a3 = (O[dt][4 * pr + 3] + v.w) * inv;
        uint2 uu;
        uu.x = packbf(a0, a1);
        uu.y = packbf(a2, a3);
        *(uint2*)(arow + dt * 32 + 8 * pr + 4 * hh) = uu;
      }
    }
  }

  // ---- lightest blocks also cast Wo -> bf16 (cos table region is dead now)
  if (qb == 0) {
    const int base = bh * 4096;
#pragma unroll
    for (int i = 0; i < 4; ++i)
      wob[base + i * 1024 + t] = f2bf(Wo[base + i * 1024 + t]);
  }
}

// ---------------------------------------------------------------------------
// Kernel 3: output projection out[tok][e] = sum_i att[tok][i] * Wob[e][i]
// ---------------------------------------------------------------------------
__global__ __launch_bounds__(256) void outproj(
    const unsigned short* __restrict__ att, const unsigned short* __restrict__ wob,
    float* __restrict__ out) {
  const int wave = threadIdx.x >> 6, lane = threadIdx.x & 63;
  const int l16 = lane & 15, quad = lane >> 4;
  const int tok0 = blockIdx.x * 16;
  const int e0 = wave * 16;

  v4f acc0 = {0.f, 0.f, 0.f, 0.f}, acc1 = {0.f, 0.f, 0.f, 0.f};
  const unsigned short* ar = att + (size_t)(tok0 + l16) * 1536 + quad * 8;
  const unsigned short* wr = wob + (size_t)(e0 + l16) * 1536 + quad * 8;
#pragma unroll 4
  for (int s = 0; s < 24; ++s) {
    v8s a0 = *(const v8s*)(ar + (2 * s) * 32);
    v8s b0 = *(const v8s*)(wr + (2 * s) * 32);
    v8s a1 = *(const v8s*)(ar + (2 * s + 1) * 32);
    v8s b1 = *(const v8s*)(wr + (2 * s + 1) * 32);
    acc0 = MFMA16(a0, b0, acc0);
    acc1 = MFMA16(a1, b1, acc1);
  }
#pragma unroll
  for (int r = 0; r < 4; ++r)
    out[(size_t)(tok0 + quad * 4 + r) * 64 + e0 + l16] = acc0[r] + acc1[r];
}

// ---------------------------------------------------------------------------
extern "C" void kernel_launch(void* const* d_in, const int* in_sizes, int n_in,
                              void* d_out, int out_size, void* d_ws,
                              size_t ws_size, hipStream_t stream) {
  const float* q  = (const float*)d_in[0];
  const float* Wq = (const float*)d_in[1];
  const float* Wk = (const float*)d_in[2];
  const float* Wv = (const float*)d_in[3];
  const float* Wo = (const float*)d_in[4];
  float* out = (float*)d_out;

  // workspace layout (bytes):
  //   qh  bf16 [2,12,2048,128]  @ 0           (Q pre-scaled by SCALE2)
  //   kh  bf16 [2,12,2048,128]  @ 12582912
  //   vtf bf16 [24][32][4][4][64][8] @ 25165824   (fragment-linear V)
  //   att bf16 [2,2048,1536]    @ 37748736
  //   cos_t f32 [2048,64]       @ 50331648  (dead after proj_rope; attn's
  //        qb==0 blocks overwrite with Wo bf16 = wob, read by outproj)
  //   sin_t f32 [2048,64]       @ 50855936   (total 51380224)
  unsigned short* ws = (unsigned short*)d_ws;
  unsigned short* qh  = ws;
  unsigned short* kh  = ws + 6291456;
  unsigned short* vtf = ws + 12582912;
  unsigned short* att = ws + 18874368;
  float* cos_t = (float*)((char*)d_ws + 50331648);
  float* sin_t = cos_t + 131072;
  unsigned short* wob = (unsigned short*)cos_t;   // reuse after proj_rope

  // attn needs 128 KB dynamic LDS (gfx950 allows 160 KB with opt-in)
  hipFuncSetAttribute((const void*)attn,
                      hipFuncAttributeMaxDynamicSharedMemorySize, 131072);

  rope_table<<<512, 256, 0, stream>>>(cos_t, sin_t);
  proj_rope<<<dim3(64, 72), 256, 0, stream>>>(q, Wq, Wk, Wv, cos_t, sin_t,
                                              qh, kh, vtf);
  attn<<<dim3(384), 1024, 131072, stream>>>(qh, kh, vtf, att, Wo, wob);
  outproj<<<256, 256, 0, stream>>>(att, wob, out);
}

// Round 7
// 179.054 us; speedup vs baseline: 1.5293x; 1.5293x over previous
//
#include <hip/hip_runtime.h>
#include <stdint.h>

// ---------------------------------------------------------------------------
// Problem: B=2, S=2048, E=64, H=12, D=128, inner=1536
// Pipeline: [QKV proj + inline RoPE -> bf16 (Q pre-scaled)] ->
//           [causal flash attn, split-K within block, 32-key tiles, K+V LDS,
//            2 blocks/CU, 32x32 MFMA, no-max softmax, + Wo cast] ->
//           [output proj]
// ---------------------------------------------------------------------------

typedef short v8s __attribute__((ext_vector_type(8)));    // 8 x bf16
typedef unsigned int v4u __attribute__((ext_vector_type(4)));
typedef float v4f __attribute__((ext_vector_type(4)));
typedef float v16f __attribute__((ext_vector_type(16)));

#define MFMA16(a, b, c) __builtin_amdgcn_mfma_f32_16x16x32_bf16(a, b, c, 0, 0, 0)
#define MFMA32(a, b, c) __builtin_amdgcn_mfma_f32_32x32x16_bf16(a, b, c, 0, 0, 0)

#if __has_builtin(__builtin_amdgcn_exp2f)
#define EXP2(x) __builtin_amdgcn_exp2f(x)
#else
#define EXP2(x) exp2f(x)
#endif

// 1/sqrt(128) * log2(e): folded into Q at projection time
#define SCALE2 (0.08838834764831845f * 1.4426950408889634f)

__device__ __forceinline__ unsigned short f2bf(float f) {
  uint32_t u = __builtin_bit_cast(uint32_t, f);
  u += 0x7FFFu + ((u >> 16) & 1u);   // round-to-nearest-even
  return (unsigned short)(u >> 16);
}

// pack two fp32 -> bf16x2 word (round-half-up) via 2 adds + v_perm_b32
__device__ __forceinline__ uint32_t packbf(float lo, float hi) {
  return __builtin_amdgcn_perm(__builtin_bit_cast(uint32_t, hi) + 0x8000u,
                               __builtin_bit_cast(uint32_t, lo) + 0x8000u,
                               0x07060302u);
}

__device__ __forceinline__ v16f zero16() {
  v16f z;
#pragma unroll
  for (int i = 0; i < 16; ++i) z[i] = 0.f;
  return z;
}

// async global->LDS, 16 B per lane. LDS dst must be wave-uniform base + lane*16.
__device__ __forceinline__ void gl_lds16(const unsigned short* g, unsigned short* l) {
  __builtin_amdgcn_global_load_lds(
      (const __attribute__((address_space(1))) uint32_t*)g,
      (__attribute__((address_space(3))) uint32_t*)l, 16, 0, 0);
}

// ---------------------------------------------------------------------------
// Kernel 1: QKV projection + INLINE RoPE + bf16 cast (rope_table kernel fused
// away: sincosf computed per element; ~16 sincosf/thread, saves one launch).
// Q additionally scaled by SCALE2 (rotation commutes with scaling).
// qh/kh: bf16 [B,H,S,D].
// V written FRAGMENT-LINEAR for attn's LDS-staged PV reads:
//   vtf[bh][kt=tok/64][G=chunk/2 (4)][dt=d/32 (4)][lane=hh*32+(d&31) (64)][8 keys]
//   where chunk=(tok%64)/8, hh=chunk&1, G=chunk>>1.
//   A 32-key subtile (2 G's) is a contiguous 8 KB run -> trivial gl_lds16
//   copy, conflict-free ds_read_b128.
// ---------------------------------------------------------------------------
__global__ __launch_bounds__(256) void proj_rope(
    const float* __restrict__ x, const float* __restrict__ Wq,
    const float* __restrict__ Wk, const float* __restrict__ Wv,
    unsigned short* __restrict__ qh, unsigned short* __restrict__ kh,
    unsigned short* __restrict__ vt) {
  const int wave = threadIdx.x >> 6, lane = threadIdx.x & 63;
  const int l16 = lane & 15, quad = lane >> 4;
  const int by = blockIdx.y;
  const int o_base = by * 64 + wave * 16;
  const int mat = o_base / 1536;                    // 0=q 1=k 2=v (block-uniform)
  const int inner0 = o_base % 1536;
  const int d0w = inner0 & 127;
  const float* Wsrc = (mat == 0) ? Wq : ((mat == 1) ? Wk : Wv);
  const float qscale = (mat == 0) ? SCALE2 : 1.0f;

  __shared__ __align__(16) unsigned short Lt[64][72];

  v8s wb[2];
  {
    const float* wr = Wsrc + (size_t)(inner0 + l16) * 64 + quad * 8;
#pragma unroll
    for (int s = 0; s < 2; ++s) {
      float4 a = *(const float4*)(wr + s * 32);
      float4 b = *(const float4*)(wr + s * 32 + 4);
      v8s t;
      t[0] = (short)f2bf(a.x); t[1] = (short)f2bf(a.y);
      t[2] = (short)f2bf(a.z); t[3] = (short)f2bf(a.w);
      t[4] = (short)f2bf(b.x); t[5] = (short)f2bf(b.y);
      t[6] = (short)f2bf(b.z); t[7] = (short)f2bf(b.w);
      wb[s] = t;
    }
  }

  const int d = d0w + l16;
  // inv_freq = 10000^(-(d/2)/64) = exp2(-(d/2) * log2(10000)/64)
  const float invf = exp2f((float)(d >> 1) * -0.20762050593046014f);

#pragma unroll
  for (int i = 0; i < 4; ++i) {
    const int tok0 = blockIdx.x * 64 + i * 16;
    const float* xr = x + (size_t)(tok0 + l16) * 64 + quad * 8;
    v8s xa[2];
#pragma unroll
    for (int s = 0; s < 2; ++s) {
      float4 a = *(const float4*)(xr + s * 32);
      float4 b = *(const float4*)(xr + s * 32 + 4);
      v8s t;
      t[0] = (short)f2bf(a.x); t[1] = (short)f2bf(a.y);
      t[2] = (short)f2bf(a.z); t[3] = (short)f2bf(a.w);
      t[4] = (short)f2bf(b.x); t[5] = (short)f2bf(b.y);
      t[6] = (short)f2bf(b.z); t[7] = (short)f2bf(b.w);
      xa[s] = t;
    }
    v4f acc = {0.f, 0.f, 0.f, 0.f};
    acc = MFMA16(xa[0], wb[0], acc);
    acc = MFMA16(xa[1], wb[1], acc);

    if (mat < 2) {
#pragma unroll
      for (int r = 0; r < 4; ++r) {
        int sidx = (tok0 + quad * 4 + r) & 2047;
        float val = acc[r];
        float prt = __shfl_xor(val, 1);   // pair partner (d^1), same token
        float ang = (float)sidx * invf;
        float si, co;
        sincosf(ang, &si, &co);
        float rot = ((d & 1) == 0) ? (val * co - prt * si)
                                   : (prt * si + val * co);
        Lt[i * 16 + quad * 4 + r][wave * 16 + l16] = f2bf(rot * qscale);
      }
    } else {
#pragma unroll
      for (int r = 0; r < 4; ++r)
        Lt[wave * 16 + l16][i * 16 + quad * 4 + r] = f2bf(acc[r]);
    }
  }
  __syncthreads();

  // cooperative b128 coalesced readout
  const int matb = (by * 64) / 1536;
  const int innerb = (by * 64) % 1536;
  const int hb = innerb >> 7;
  const int d0b = innerb & 127;
  const int b = (blockIdx.x * 64) >> 11;
  const int tokbase = (blockIdx.x * 64) & 2047;
#pragma unroll
  for (int jj = 0; jj < 2; ++jj) {
    int cid = jj * 256 + threadIdx.x;
    int outer = cid >> 3, ic = cid & 7;
    v8s val = *(const v8s*)&Lt[outer][ic * 8];
    if (matb < 2) {
      unsigned short* dst = (matb == 0 ? qh : kh) +
          (((size_t)(b * 12 + hb)) * 2048 + tokbase + outer) * 128 + d0b + ic * 8;
      *(v8s*)dst = val;
    } else {
      // fragment-linear vtf store: Lt[outer][ic*8+e] = V^T[d0b+outer][tokbase+ic*8+e]
      const int kt = tokbase >> 6;
      const int G = ic >> 1, hhb = ic & 1;
      const int dd = d0b + outer;
      unsigned short* dst = vt +
          ((((((size_t)(b * 12 + hb)) * 32 + kt) * 4 + G) * 4 + (dd >> 5)) * 64 +
           hhb * 32 + (dd & 31)) * 8;
      *(v8s*)dst = val;
    }
  }
}

// ---------------------------------------------------------------------------
// Kernel 2: causal flash attention. SPLIT-K within block, 32-KEY TILES,
// 64KB LDS -> 2 BLOCKS/CU (4 waves/SIMD on paired CUs).
// R6 post-mortem: any VGPR cap of 128 makes hipcc collapse to 64 + scratch
// spill (R3, R6) -> 16-wave blocks are off the table. More waves/SIMD must
// come from 2 co-resident 8-wave blocks: LDS <= 64KB and natural VGPR ~96
// (<=128) with a 256 cap declared via (512,2).
// Structure: 512 thr = 8 waves = 4 row-groups x 2 key-herds; herd h owns
// 32-key tiles [h*NS, (h+1)*NS), NS = 2qb+2. Same per-wave work and staging
// volume as R5; steps are half-size, twice as many. Exact linear combine
// (no max-rescale) via R4's 4-phase epilogue over the 64KB LDS.
// Pairing (all 384 blocks resident; n and n+256 share a CU, same XCD since
// 256%8==0): heavy at n<128 = {qb15..11 x24, 8x qb5}; partners at n+256 =
// {qb6..10 x24, 8x qb5} -> pair step-sums ~46 const; singles n in [128,256)
// = {qb5 x8, qb4..0 x24} finish early. Critical qb15 blocks always have a
// co-resident partner filling their dependency stalls.
// qb==0 blocks (lightest) also cast Wo->bf16 into the dead table region.
// ---------------------------------------------------------------------------
__global__ __launch_bounds__(512, 2) void attn(
    const unsigned short* __restrict__ qh, const unsigned short* __restrict__ kh,
    const unsigned short* __restrict__ vtf, unsigned short* __restrict__ att,
    const float* __restrict__ Wo, unsigned short* __restrict__ wob) {
  extern __shared__ __align__(16) unsigned short SH[];
  unsigned short* KSH = SH;            // 4 slots (herd*2+buf) x 4096 shorts [32 KB]
  unsigned short* VSH = SH + 16384;    // 4 slots x 4096 shorts              [32 KB]

  // ---- pairing decode (see header)
  const int n = blockIdx.x;
  int qb, bh;
  if (n < 128) {                        // pair primaries (heavy)
    if (n < 120) { qb = 15 - n / 24; bh = n % 24; }    // qb15..11
    else         { qb = 5; bh = n - 120; }             // qb5 bh0..7
  } else if (n < 256) {                 // singles (light)
    int m = n - 128;
    if (m < 8)        { qb = 5; bh = 16 + m; }         // qb5 bh16..23
    else if (m < 32)  { qb = 4; bh = m - 8; }
    else if (m < 56)  { qb = 3; bh = m - 32; }
    else if (m < 80)  { qb = 2; bh = m - 56; }
    else if (m < 104) { qb = 1; bh = m - 80; }
    else              { qb = 0; bh = m - 104; }
  } else {                              // pair secondaries
    int r = n - 256;
    if (r < 24)       { qb = 6;  bh = r; }
    else if (r < 48)  { qb = 7;  bh = r - 24; }
    else if (r < 72)  { qb = 8;  bh = r - 48; }
    else if (r < 96)  { qb = 9;  bh = r - 72; }
    else if (r < 120) { qb = 10; bh = r - 96; }
    else              { qb = 5;  bh = 8 + (r - 120); } // qb5 bh8..15
  }

  const int t = threadIdx.x;
  const int lane = t & 63;
  const int l31 = lane & 31, hh = lane >> 5;
  const int w = t >> 6;                          // 8 waves
  const int rg = w & 3, kherd = w >> 2;          // row-group / key-range half
  const int r0w = qb * 128 + rg * 32;
  const int qrow = r0w + l31;
  const int rowmax = r0w + 31;

  const unsigned short* Qb = qh + (size_t)bh * 2048 * 128;
  const unsigned short* Kb = kh + (size_t)bh * 2048 * 128;
  const unsigned short* Vb = vtf + (size_t)bh * 262144;   // 32*4*4*64*8

  // Q fragments (serve as MFMA B-operand): Q[qrow][ks*16 + hh*8 + j]
  v8s qa[8];
  {
    const unsigned short* qr = Qb + (size_t)qrow * 128 + hh * 8;
#pragma unroll
    for (int ks = 0; ks < 8; ++ks) qa[ks] = *(const v8s*)(qr + ks * 16);
  }

  const int NS = 2 * qb + 2;             // 32-key steps per herd

  // staging: thread t stages its own herd's (t>>8 == kherd) next tile.
  // Per round: 256 threads x 16B = 4KB; two rounds each for K (8KB swizzled)
  // and V (8KB identity, fragment-linear).
  const int th = t & 255;
  int offK[2];
#pragma unroll
  for (int j = 0; j < 2; ++j) {
    int flat = th + 256 * j;
    int kr = flat >> 4, kc = flat & 15;
    offK[j] = kr * 128 + ((kc ^ (kr & 15)) << 3);
  }
  auto stage = [&](int i1) {
    const int kt = kherd * NS + i1;      // this herd's 32-key tile index
    const int slot = kherd * 2 + (i1 & 1);
    const unsigned short* kg = Kb + ((size_t)kt << 5) * 128;
    const unsigned short* vg = Vb + (size_t)kt * 4096;
#pragma unroll
    for (int j = 0; j < 2; ++j) {
      const int flat = th + 256 * j;
      gl_lds16(kg + offK[j], KSH + slot * 4096 + (flat << 3));
      gl_lds16(vg + (flat << 3), VSH + slot * 4096 + (flat << 3));
    }
  };

  v16f O[4];
#pragma unroll
  for (int i = 0; i < 4; ++i) O[i] = zero16();
  float lsum = 0.f;

  stage(0);
  asm volatile("s_waitcnt vmcnt(0)" ::: "memory");

  for (int i = 0; i < NS; ++i) {
    __builtin_amdgcn_s_barrier();          // publishes step-i tiles (both herds)
    __builtin_amdgcn_sched_barrier(0);
    const int kt = kherd * NS + i;
    const int key0 = kt << 5;
    const bool active = key0 <= rowmax;

    // ---- next step's DMA (issued first; covered by compute)
    if (i + 1 < NS) stage(i + 1);
    __builtin_amdgcn_sched_barrier(0);

    if (active) {
      const unsigned short* Kl = KSH + (kherd * 2 + (i & 1)) * 4096;
      const unsigned short* Vl = VSH + (kherd * 2 + (i & 1)) * 4096;
      const bool mask0 = (key0 + 31) > r0w;

      // ---- S^T = K·Q^T (two independent 4-deep chains)
      v16f Sa = zero16(), Sb = zero16();
      __builtin_amdgcn_s_setprio(1);
#pragma unroll
      for (int ks = 0; ks < 8; ks += 2) {
        v8s ka0 = *(const v8s*)(
            Kl + ((l31 * 16 + ((2 * ks + hh) ^ (l31 & 15))) << 3));
        v8s ka1 = *(const v8s*)(
            Kl + ((l31 * 16 + ((2 * ks + 2 + hh) ^ (l31 & 15))) << 3));
        Sa = MFMA32(ka0, qa[ks], Sa);
        Sb = MFMA32(ka1, qa[ks + 1], Sb);
      }
      __builtin_amdgcn_s_setprio(0);

      // ---- softpack: S^T tile -> packed bf16 P-words + lsum
      uint32_t W[8];
#pragma unroll
      for (int m = 0; m < 8; ++m) {
        float pa = EXP2(Sa[2 * m] + Sb[2 * m]);
        float pb = EXP2(Sa[2 * m + 1] + Sb[2 * m + 1]);
        if (mask0) {
          int keyb = key0 + 2 * (m & 1) + 8 * (m >> 1) + 4 * hh;
          pa = (keyb <= qrow) ? pa : 0.f;
          pb = (keyb + 1 <= qrow) ? pb : 0.f;
        }
        lsum += pa + pb;
        W[m] = packbf(pa, pb);
      }

      // ---- pv: build B-operand P frags (word swap across lane^32), mult V^T
      uint32_t r0 = __shfl_xor(hh ? W[0] : W[2], 32);
      uint32_t r1 = __shfl_xor(hh ? W[1] : W[3], 32);
      uint32_t r2 = __shfl_xor(hh ? W[4] : W[6], 32);
      uint32_t r3 = __shfl_xor(hh ? W[5] : W[7], 32);
#pragma unroll
      for (int g = 0; g < 2; ++g) {
        if (key0 + g * 16 > rowmax) continue;   // wave-uniform skip
        uint32_t rA = g ? r2 : r0, rB = g ? r3 : r1;
        v4u fw;
        fw.x = hh ? rA : W[4 * g];
        fw.y = hh ? rB : W[4 * g + 1];
        fw.z = hh ? W[4 * g + 2] : rA;
        fw.w = hh ? W[4 * g + 3] : rB;
        v8s pfrag = __builtin_bit_cast(v8s, fw);
        __builtin_amdgcn_s_setprio(1);
#pragma unroll
        for (int dt = 0; dt < 4; ++dt) {
          v8s va = *(const v8s*)(Vl + (((g * 4 + dt) * 64 + lane) << 3));
          O[dt] = MFMA32(va, pfrag, O[dt]);
        }
        __builtin_amdgcn_s_setprio(0);
      }
    }
    // staged DMA must retire before next barrier publishes the buffers
    asm volatile("s_waitcnt vmcnt(0)" ::: "memory");
  }

  // ---- split-K reduce, 4 phases over the 64KB LDS (dead after loop):
  //   (1) upper herd dumps O fp32 (XOR-swizzled float4, 64KB exactly),
  //   (2) lower accumulates, (3) upper dumps lsum over consumed region,
  //   (4) lower normalizes + stores att.
  __syncthreads();
  float* Ored = (float*)SH;              // [rg][l31][128] XOR-swizzled
  if (kherd == 1) {
    float* baseO = Ored + rg * 4096 + l31 * 128;
#pragma unroll
    for (int dt = 0; dt < 4; ++dt)
#pragma unroll
      for (int pr = 0; pr < 4; ++pr) {
        float4 v;
        v.x = O[dt][4 * pr + 0]; v.y = O[dt][4 * pr + 1];
        v.z = O[dt][4 * pr + 2]; v.w = O[dt][4 * pr + 3];
        *(float4*)(baseO + dt * 32 + (((2 * pr + hh) ^ (l31 & 7)) << 2)) = v;
      }
  }
  __syncthreads();
  if (kherd == 0) {
    const float* baseO = Ored + rg * 4096 + l31 * 128;
#pragma unroll
    for (int dt = 0; dt < 4; ++dt)
#pragma unroll
      for (int pr = 0; pr < 4; ++pr) {
        float4 v = *(const float4*)(
            baseO + dt * 32 + (((2 * pr + hh) ^ (l31 & 7)) << 2));
        O[dt][4 * pr + 0] += v.x;
        O[dt][4 * pr + 1] += v.y;
        O[dt][4 * pr + 2] += v.z;
        O[dt][4 * pr + 3] += v.w;
      }
  }
  __syncthreads();
  if (kherd == 1) Ored[rg * 64 + lane] = lsum;
  __syncthreads();
  if (kherd == 0) {
    const float lt = lsum + Ored[rg * 64 + lane];
    const float tot = lt + __shfl_xor(lt, 32);
    const float inv = 1.0f / tot;
    const int b = bh / 12, hq = bh % 12;
    unsigned short* arow = att + ((size_t)b * 2048 + qrow) * 1536 + hq * 128;
#pragma unroll
    for (int dt = 0; dt < 4; ++dt) {
#pragma unroll
      for (int pr = 0; pr < 4; ++pr) {
        float a0 = O[dt][4 * pr + 0] * inv;
        float a1 = O[dt][4 * pr + 1] * inv;
        float a2 = O[dt][4 * pr + 2] * inv;
        float a3 = O[dt][4 * pr + 3] * inv;
        uint2 uu;
        uu.x = packbf(a0, a1);
        uu.y = packbf(a2, a3);
        *(uint2*)(arow + dt * 32 + 8 * pr + 4 * hh) = uu;
      }
    }
  }

  // ---- lightest blocks also cast Wo -> bf16 (dead table region = wob)
  if (qb == 0) {
    const int base = bh * 4096;
#pragma unroll
    for (int i = 0; i < 8; ++i)
      wob[base + i * 512 + t] = f2bf(Wo[base + i * 512 + t]);
  }
}

// ---------------------------------------------------------------------------
// Kernel 3: output projection out[tok][e] = sum_i att[tok][i] * Wob[e][i]
// ---------------------------------------------------------------------------
__global__ __launch_bounds__(256) void outproj(
    const unsigned short* __restrict__ att, const unsigned short* __restrict__ wob,
    float* __restrict__ out) {
  const int wave = threadIdx.x >> 6, lane = threadIdx.x & 63;
  const int l16 = lane & 15, quad = lane >> 4;
  const int tok0 = blockIdx.x * 16;
  const int e0 = wave * 16;

  v4f acc0 = {0.f, 0.f, 0.f, 0.f}, acc1 = {0.f, 0.f, 0.f, 0.f};
  const unsigned short* ar = att + (size_t)(tok0 + l16) * 1536 + quad * 8;
  const unsigned short* wr = wob + (size_t)(e0 + l16) * 1536 + quad * 8;
#pragma unroll 4
  for (int s = 0; s < 24; ++s) {
    v8s a0 = *(const v8s*)(ar + (2 * s) * 32);
    v8s b0 = *(const v8s*)(wr + (2 * s) * 32);
    v8s a1 = *(const v8s*)(ar + (2 * s + 1) * 32);
    v8s b1 = *(const v8s*)(wr + (2 * s + 1) * 32);
    acc0 = MFMA16(a0, b0, acc0);
    acc1 = MFMA16(a1, b1, acc1);
  }
#pragma unroll
  for (int r = 0; r < 4; ++r)
    out[(size_t)(tok0 + quad * 4 + r) * 64 + e0 + l16] = acc0[r] + acc1[r];
}

// ---------------------------------------------------------------------------
extern "C" void kernel_launch(void* const* d_in, const int* in_sizes, int n_in,
                              void* d_out, int out_size, void* d_ws,
                              size_t ws_size, hipStream_t stream) {
  const float* q  = (const float*)d_in[0];
  const float* Wq = (const float*)d_in[1];
  const float* Wk = (const float*)d_in[2];
  const float* Wv = (const float*)d_in[3];
  const float* Wo = (const float*)d_in[4];
  float* out = (float*)d_out;

  // workspace layout (bytes):
  //   qh  bf16 [2,12,2048,128]  @ 0           (Q pre-scaled by SCALE2)
  //   kh  bf16 [2,12,2048,128]  @ 12582912
  //   vtf bf16 [24][32][4][4][64][8] @ 25165824   (fragment-linear V)
  //   att bf16 [2,2048,1536]    @ 37748736
  //   wob bf16 [64,1536]        @ 50331648  (written by attn qb==0 blocks,
  //        read by outproj; rope table is gone — sincos inlined)
  unsigned short* ws = (unsigned short*)d_ws;
  unsigned short* qh  = ws;
  unsigned short* kh  = ws + 6291456;
  unsigned short* vtf = ws + 12582912;
  unsigned short* att = ws + 18874368;
  unsigned short* wob = ws + 25165824;

  // attn uses 64 KB dynamic LDS
  hipFuncSetAttribute((const void*)attn,
                      hipFuncAttributeMaxDynamicSharedMemorySize, 65536);

  proj_rope<<<dim3(64, 72), 256, 0, stream>>>(q, Wq, Wk, Wv, qh, kh, vtf);
  attn<<<dim3(384), 512, 65536, stream>>>(qh, kh, vtf, att, Wo, wob);
  outproj<<<256, 256, 0, stream>>>(att, wob, out);
}